// Round 1
// baseline (263.787 us; speedup 1.0000x reference)
//
#include <hip/hip_runtime.h>

typedef short bf16x8 __attribute__((ext_vector_type(8)));
typedef float f32x4 __attribute__((ext_vector_type(4)));

#define B_ 32
#define C_ 256
#define H_ 56
#define W_ 56
#define HP 58
#define WP 58

static constexpr float QSCALE = 255.0f / 8.0f;   // 31.875 (exact in fp32)
static constexpr float D1 = 8.0f / 255.0f;

static constexpr size_t XP_ELEMS = (size_t)B_ * HP * WP * C_;   // 27,541,504
static constexpr size_t XP_BYTES = XP_ELEMS * 2;                // 55,083,008
static constexpr size_t WT_ELEMS = 9ull * C_ * C_;              // 589,824
static constexpr size_t WT_BYTES = WT_ELEMS * 2;

__device__ __forceinline__ unsigned short f32_to_bf16_rne(float f) {
  unsigned int u = __builtin_bit_cast(unsigned int, f);
  u += 0x7FFFu + ((u >> 16) & 1u);
  return (unsigned short)(u >> 16);
}

__device__ __forceinline__ void gload_lds16(const void* g, void* l) {
  __builtin_amdgcn_global_load_lds((const __attribute__((address_space(1))) unsigned int*)g,
                                   (__attribute__((address_space(3))) unsigned int*)l,
                                   16, 0, 0);
}

// ---------------- Kernel 1: quantize + NCHW -> padded NHWC (bf16 integer levels) -----------
__global__ __launch_bounds__(256) void quant_transpose(const float* __restrict__ x,
                                                       unsigned short* __restrict__ Xp) {
  __shared__ unsigned short T[W_ * 256];     // [w][c], 28,672 B
  const int h = blockIdx.x;
  const int b = blockIdx.y;
  const int c = threadIdx.x;

  const float4* src = (const float4*)(x + (((size_t)b * C_ + c) * H_ + h) * W_);
#pragma unroll
  for (int i = 0; i < 14; ++i) {
    float4 v = src[i];
    float vals[4] = {v.x, v.y, v.z, v.w};
    const int w0 = i * 4;
#pragma unroll
    for (int j = 0; j < 4; ++j) {
      int n = (int)rintf(vals[j] * QSCALE);
      n = n < 0 ? 0 : (n > 255 ? 255 : n);
      // small integers are exact in bf16: truncate fp32
      T[(w0 + j) * 256 + c] = (unsigned short)(__builtin_bit_cast(unsigned int, (float)n) >> 16);
    }
  }
  __syncthreads();

  const int wid = threadIdx.x >> 6;
  const int lane = threadIdx.x & 63;
#pragma unroll
  for (int p = 0; p < 14; ++p) {
    const int w = p * 4 + wid;
    ushort4 v = *(const ushort4*)&T[w * 256 + lane * 4];
    *(ushort4*)(Xp + (((size_t)b * HP + (h + 1)) * WP + (w + 1)) * 256 + lane * 4) = v;
  }
}

// ---------------- Kernel 2: weights * d1 -> bf16, layout [pos][co][ci] ---------------------
__global__ __launch_bounds__(256) void prep_weights(const float* __restrict__ w,
                                                    unsigned short* __restrict__ Wt) {
  const int co = blockIdx.x;
  const int ci = threadIdx.x;
  const float* src = w + ((size_t)co * 256 + ci) * 9;
#pragma unroll
  for (int p = 0; p < 9; ++p) {
    Wt[((size_t)p * 256 + co) * 256 + ci] = f32_to_bf16_rne(src[p] * D1);
  }
}

// ---------------- Kernel 3: implicit-GEMM conv, bf16 MFMA 16x16x32 -------------------------
// block: 256 threads (4 waves). BM=128 c_out, 2 output rows (BN=112), c_in chunks of 64.
__global__ __launch_bounds__(256) void conv_mfma(const unsigned short* __restrict__ Xp,
                                                 const unsigned short* __restrict__ Wt,
                                                 float* __restrict__ out) {
  __shared__ __align__(16) unsigned short Xlds[256 * 64];   // 256 rows x 64 ch = 32 KB
  const int tid = threadIdx.x;
  const int wid = tid >> 6, lane = tid & 63;
  const int col = lane & 15, hi = lane >> 4;
  const int mb = blockIdx.x * 128;
  const int by = blockIdx.y;            // output rows 2*by, 2*by+1
  const int b = blockIdx.z;
  const int h0 = 2 * by;                // padded row of first needed input row

  int nbase[7];
#pragma unroll
  for (int nf = 0; nf < 7; ++nf) {
    const int n_out = nf * 16 + col;
    const int r = n_out >= 56 ? 1 : 0;
    nbase[nf] = r * WP + (n_out - r * 56);
  }

  f32x4 acc[2][7];
#pragma unroll
  for (int mf = 0; mf < 2; ++mf)
#pragma unroll
    for (int nf = 0; nf < 7; ++nf) acc[mf][nf] = (f32x4){0.f, 0.f, 0.f, 0.f};

  const size_t xbase = ((size_t)b * HP + h0) * WP * 256;

  for (int cc = 0; cc < 4; ++cc) {
    const int c0 = cc * 64;
    // ---- stage X tile: rows (h0..h0+3) x 58 cols x 64 ch, slot-swizzled source ----
#pragma unroll
    for (int pass = 0; pass < 8; ++pass) {
      const int s = pass * 256 + tid;       // 16B slot index, linear LDS dest
      const int nrow = s >> 3;              // 0..255 (rows 232..255 load unused garbage in-ws)
      const int cslot = s & 7;
      const int cdat = cslot ^ (nrow & 7);  // pre-swizzled source slot
      const int hh = nrow / WP;
      const int wp = nrow - hh * WP;
      const unsigned short* g = Xp + xbase + ((size_t)hh * WP + wp) * 256 + c0 + cdat * 8;
      gload_lds16(g, (char*)Xlds + s * 16);
    }
    __syncthreads();

    // ---- compute: 9 kernel positions x 2 k-steps x 7 n-frags, 2 m-frags/wave ----
#pragma unroll
    for (int pos = 0; pos < 9; ++pos) {
      const int kh = pos / 3, kw = pos % 3;
      const int poff = kh * WP + kw;
      const unsigned short* wbase =
          Wt + (size_t)pos * 65536 + (size_t)(mb + wid * 32 + col) * 256 + c0 + hi * 8;
#pragma unroll
      for (int ks = 0; ks < 2; ++ks) {
        bf16x8 a0 = *(const bf16x8*)(wbase + ks * 32);
        bf16x8 a1 = *(const bf16x8*)(wbase + 16 * 256 + ks * 32);
#pragma unroll
        for (int nf = 0; nf < 7; ++nf) {
          const int nin = nbase[nf] + poff;
          const int cs = ks * 4 + hi;
          const int sw = cs ^ (nin & 7);
          bf16x8 bfr = *(const bf16x8*)((const char*)Xlds + nin * 128 + sw * 16);
          acc[0][nf] = __builtin_amdgcn_mfma_f32_16x16x32_bf16(a0, bfr, acc[0][nf], 0, 0, 0);
          acc[1][nf] = __builtin_amdgcn_mfma_f32_16x16x32_bf16(a1, bfr, acc[1][nf], 0, 0, 0);
        }
      }
    }
    __syncthreads();
  }

  // ---- epilogue: C[row=c_out][col=spatial]; row=(lane>>4)*4+r, col=lane&15 ----
#pragma unroll
  for (int mf = 0; mf < 2; ++mf) {
#pragma unroll
    for (int nf = 0; nf < 7; ++nf) {
      const int n_out = nf * 16 + col;
      const int r = n_out >= 56 ? 1 : 0;
      const int hrow = h0 + r;
      const int wcol = n_out - r * 56;
      const int cbase = mb + wid * 32 + mf * 16 + hi * 4;
      float* o = out + ((((size_t)b * 256 + cbase) * 56 + hrow) * 56 + wcol);
#pragma unroll
      for (int r4 = 0; r4 < 4; ++r4) o[(size_t)r4 * 56 * 56] = acc[mf][nf][r4];
    }
  }
}

// ---------------- Fallback: naive direct conv (if ws too small) ----------------------------
__global__ void conv_naive(const float* __restrict__ x, const float* __restrict__ w,
                           float* __restrict__ out, int total) {
  int idx = blockIdx.x * 256 + threadIdx.x;
  if (idx >= total) return;
  const int wc = idx % 56;
  int t = idx / 56;
  const int hr = t % 56; t /= 56;
  const int co = t % 256;
  const int b = t / 256;
  float acc = 0.f;
  for (int ci = 0; ci < 256; ++ci) {
    const float* xb = x + (((size_t)b * 256 + ci) * 56) * 56;
    const float* wb = w + ((size_t)co * 256 + ci) * 9;
#pragma unroll
    for (int kh = 0; kh < 3; ++kh) {
      const int hh = hr + kh - 1;
      if (hh < 0 || hh >= 56) continue;
#pragma unroll
      for (int kw = 0; kw < 3; ++kw) {
        const int ww = wc + kw - 1;
        if (ww < 0 || ww >= 56) continue;
        const float q = rintf(xb[hh * 56 + ww] * QSCALE) * D1;
        acc += q * wb[kh * 3 + kw];
      }
    }
  }
  out[idx] = acc;
}

extern "C" void kernel_launch(void* const* d_in, const int* in_sizes, int n_in,
                              void* d_out, int out_size, void* d_ws, size_t ws_size,
                              hipStream_t stream) {
  (void)in_sizes; (void)n_in; (void)out_size;
  const float* x = (const float*)d_in[0];
  const float* w = (const float*)d_in[1];
  float* out = (float*)d_out;

  if (ws_size < XP_BYTES + WT_BYTES) {
    const int total = B_ * C_ * H_ * W_;
    conv_naive<<<(total + 255) / 256, 256, 0, stream>>>(x, w, out, total);
    return;
  }

  unsigned short* Xp = (unsigned short*)d_ws;
  unsigned short* Wt = (unsigned short*)((char*)d_ws + XP_BYTES);

  hipMemsetAsync(d_ws, 0, XP_BYTES, stream);                 // zero padding border
  quant_transpose<<<dim3(56, 32), 256, 0, stream>>>(x, Xp);
  prep_weights<<<dim3(256), 256, 0, stream>>>(w, Wt);
  conv_mfma<<<dim3(2, 28, 32), 256, 0, stream>>>(Xp, Wt, out);
}